// Round 7
// baseline (799.498 us; speedup 1.0000x reference)
//
#include <hip/hip_runtime.h>
#include <hip/hip_bf16.h>

#define T_TOK 4096
#define DM 1024
#define DF 4096
#define NE 8

typedef __attribute__((ext_vector_type(4))) float f32x4;
typedef __attribute__((ext_vector_type(8))) short bf16x8;

__device__ inline unsigned short f2bf(float f) {
  union { float f; unsigned u; } a; a.f = f;
  unsigned r = a.u + 0x7fffu + ((a.u >> 16) & 1u);
  return (unsigned short)(r >> 16);
}
__device__ inline unsigned pk(float lo, float hi) {
  return (unsigned)f2bf(lo) | ((unsigned)f2bf(hi) << 16);
}
__device__ inline float bf2f(unsigned short u) {
  union { unsigned u; float f; } a; a.u = ((unsigned)u) << 16; return a.f;
}

// async global->LDS, 16B per lane. LDS dest must be (wave-uniform base + lane*16).
__device__ inline void gload16(const void* g, void* l) {
  __builtin_amdgcn_global_load_lds(
      (const __attribute__((address_space(1))) unsigned int*)g,
      (__attribute__((address_space(3))) unsigned int*)l, 16, 0, 0);
}

// ---------------- router ----------------
__global__ __launch_bounds__(256) void k_router(const float* __restrict__ x,
    const float* __restrict__ Wr, const float* __restrict__ br,
    int* __restrict__ topi, float* __restrict__ topw, int* __restrict__ counts) {
  int t = blockIdx.x;
  int tid = threadIdx.x;
  const float* xr = x + (size_t)t * DM;
  float acc[NE];
#pragma unroll
  for (int e = 0; e < NE; e++) acc[e] = 0.f;
  for (int d = tid; d < DM; d += 256) {
    float xv = xr[d];
    const float* w = Wr + (size_t)d * NE;
#pragma unroll
    for (int e = 0; e < NE; e++) acc[e] += xv * w[e];
  }
  __shared__ float red[NE][256];
#pragma unroll
  for (int e = 0; e < NE; e++) red[e][tid] = acc[e];
  __syncthreads();
  for (int s = 128; s > 0; s >>= 1) {
    if (tid < s) {
#pragma unroll
      for (int e = 0; e < NE; e++) red[e][tid] += red[e][tid + s];
    }
    __syncthreads();
  }
  if (tid == 0) {
    float l[NE];
#pragma unroll
    for (int e = 0; e < NE; e++) l[e] = red[e][0] + br[e];
    int i0 = 0;
#pragma unroll
    for (int e = 1; e < NE; e++) if (l[e] > l[i0]) i0 = e;
    int i1 = (i0 == 0) ? 1 : 0;
#pragma unroll
    for (int e = 0; e < NE; e++) if (e != i0 && l[e] > l[i1]) i1 = e;
    float w1e = expf(l[i1] - l[i0]);
    float w0 = 1.f / (1.f + w1e);
    topi[2 * t] = i0; topi[2 * t + 1] = i1;
    topw[2 * t] = w0; topw[2 * t + 1] = w1e * w0;
    atomicAdd(&counts[i0], 1);
    atomicAdd(&counts[i1], 1);
  }
}

// ---------------- scan: offsets + cv^2 ----------------
__global__ void k_scan(const int* __restrict__ counts, int* __restrict__ offsets,
                       float* __restrict__ cv2out) {
  if (threadIdx.x == 0) {
    int off = 0;
    float util[NE];
    for (int e = 0; e < NE; e++) { offsets[e] = off; off += counts[e]; }
    offsets[NE] = off;
    float mean = 0.f;
    for (int e = 0; e < NE; e++) { util[e] = (float)counts[e] / (float)(2 * T_TOK); mean += util[e]; }
    mean *= (1.f / NE);
    float var = 0.f;
    for (int e = 0; e < NE; e++) { float d = util[e] - mean; var += d * d; }
    var *= (1.f / (NE - 1));
    float den = mean + 1e-6f;
    *cv2out = var / (den * den);
  }
}

// ---------------- scatter ----------------
__global__ __launch_bounds__(256) void k_scatter(const int* __restrict__ topi,
    const int* __restrict__ offsets, int* __restrict__ cursor,
    int* __restrict__ perm, int* __restrict__ tslot) {
  int t = blockIdx.x * 256 + threadIdx.x;
  if (t >= T_TOK) return;
#pragma unroll
  for (int k = 0; k < 2; k++) {
    int e = topi[2 * t + k];
    int p = atomicAdd(&cursor[e], 1);
    int s = offsets[e] + p;
    perm[s] = t;
    tslot[2 * t + k] = s;
  }
}

// ---------------- cvtx: x f32 -> bf16 ----------------
__global__ __launch_bounds__(256) void k_cvtx(const float* __restrict__ x,
    unsigned short* __restrict__ xc) {
  size_t i = ((size_t)blockIdx.x * 256 + threadIdx.x) * 8;
  f32x4 a = *(const f32x4*)(x + i);
  f32x4 b = *(const f32x4*)(x + i + 4);
  uint4 v;
  v.x = pk(a[0], a[1]); v.y = pk(a[2], a[3]);
  v.z = pk(b[0], b[1]); v.w = pk(b[2], b[3]);
  *(uint4*)(xc + i) = v;
}

// ---------------- cvtT: W [e][K][N] f32 -> Wt [e][N][K] bf16 (transpose+convert) ---------
__global__ __launch_bounds__(256) void k_cvtT(const float* __restrict__ src,
    unsigned short* __restrict__ dst, int K, int N) {
  int e = blockIdx.z;
  int n0 = blockIdx.x * 64, k0 = blockIdx.y * 64;
  int tid = threadIdx.x;
  __shared__ float tile[64][65];
  const float* s = src + (size_t)e * K * N + (size_t)k0 * N + n0;
  int r0 = tid >> 4, c4 = (tid & 15) * 4;
#pragma unroll
  for (int i = 0; i < 4; i++) {
    int r = r0 + i * 16;
    float4 v = *(const float4*)(s + (size_t)r * N + c4);
    tile[r][c4] = v.x; tile[r][c4 + 1] = v.y; tile[r][c4 + 2] = v.z; tile[r][c4 + 3] = v.w;
  }
  __syncthreads();
  int n = tid >> 2, kc = (tid & 3) * 16;
  unsigned o[8];
#pragma unroll
  for (int j = 0; j < 8; j++)
    o[j] = pk(tile[kc + 2 * j][n], tile[kc + 2 * j + 1][n]);
  unsigned short* dp = dst + (size_t)e * N * K + (size_t)(n0 + n) * K + k0 + kc;
  *(uint4*)dp = make_uint4(o[0], o[1], o[2], o[3]);
  *(uint4*)(dp + 8) = make_uint4(o[4], o[5], o[6], o[7]);
}

// ======================= pipelined grouped GEMM core =======================
// Double-buffered LDS, depth-1 prefetch, raw s_barrier + counted vmcnt(8):
// per step {STAGE(t+1) | vmcnt(8) | bar | ds_read+MFMA(t) | lgkmcnt(0) | bar}.
// The 8 loads of t+1 stay in flight across the barrier (T3/T4, m194-m201).

// ---------------- gemm1: hb = gelu(gather(xc) @ W1t^T + b1) ----------------
__global__ __launch_bounds__(256) void k_gemm1(const unsigned short* __restrict__ xc,
    const unsigned short* __restrict__ W1t, const float* __restrict__ b1,
    const int* __restrict__ offsets, const int* __restrict__ perm,
    unsigned short* __restrict__ hb) {
  int e = blockIdx.z;
  int roff = offsets[e];
  int nrows = offsets[e + 1] - roff;
  int row_base = blockIdx.y * 128;
  if (row_base >= nrows) return;
  int n0 = blockIdx.x * 128;
  int tid = threadIdx.x, lane = tid & 63, wid = tid >> 6;
  int wm = (wid >> 1) * 64, wn = (wid & 1) * 64;

  __shared__ __align__(16) unsigned short smA[2][128 * 64];
  __shared__ __align__(16) unsigned short smB[2][128 * 64];
  __shared__ int tok_s[128];
  if (tid < 128) {
    int r = row_base + tid;
    tok_s[tid] = (r < nrows) ? perm[roff + r] : 0;
  }
  __syncthreads();

  f32x4 acc[4][4];
#pragma unroll
  for (int m = 0; m < 4; m++)
#pragma unroll
    for (int n = 0; n < 4; n++) acc[m][n] = (f32x4)(0.f);

  const unsigned short* Bbase = W1t + (size_t)e * DF * DM + (size_t)n0 * DM;

  const unsigned short* aP[4];
  const unsigned short* bP[4];
  int ldsOff[4];
#pragma unroll
  for (int i = 0; i < 4; i++) {
    int c = tid + i * 256;
    int row = c >> 3;
    int o = ((c & 7) ^ (row & 7)) * 8;   // inverse of read-side XOR swizzle
    aP[i] = xc + (size_t)tok_s[row] * DM + o;
    bP[i] = Bbase + (size_t)row * DM + o;
    ldsOff[i] = c * 8;
  }
  // loop-invariant LDS read byte-offsets (hoisted addressing)
  int rA[2][4], rB[2][4];
#pragma unroll
  for (int ks = 0; ks < 2; ks++) {
#pragma unroll
    for (int m = 0; m < 4; m++) {
      int rowa = wm + m * 16 + (lane & 15);
      int rowb = wn + m * 16 + (lane & 15);
      int col = ks * 64 + (lane >> 4) * 16;
      rA[ks][m] = rowa * 128 + (col ^ ((rowa & 7) << 4));
      rB[ks][m] = rowb * 128 + (col ^ ((rowb & 7) << 4));
    }
  }

#define STAGE1(kk, p)                                        \
  {                                                          \
    int k0_ = (kk) * 64;                                     \
    _Pragma("unroll")                                        \
    for (int i = 0; i < 4; i++) {                            \
      gload16(aP[i] + k0_, &smA[p][ldsOff[i]]);              \
      gload16(bP[i] + k0_, &smB[p][ldsOff[i]]);              \
    }                                                        \
  }
#define COMPUTE1(p)                                                            \
  {                                                                            \
    const char* A_ = (const char*)smA[p];                                      \
    const char* B_ = (const char*)smB[p];                                      \
    _Pragma("unroll")                                                          \
    for (int ks = 0; ks < 2; ks++) {                                           \
      bf16x8 af[4], bfr[4];                                                    \
      _Pragma("unroll")                                                        \
      for (int m = 0; m < 4; m++) af[m] = *(const bf16x8*)(A_ + rA[ks][m]);    \
      _Pragma("unroll")                                                        \
      for (int n = 0; n < 4; n++) bfr[n] = *(const bf16x8*)(B_ + rB[ks][n]);   \
      _Pragma("unroll")                                                        \
      for (int m = 0; m < 4; m++)                                              \
        _Pragma("unroll")                                                      \
        for (int n = 0; n < 4; n++)                                            \
          acc[m][n] = __builtin_amdgcn_mfma_f32_16x16x32_bf16(af[m], bfr[n],   \
                                                              acc[m][n], 0, 0, 0); \
    }                                                                          \
  }

  STAGE1(0, 0);
  for (int t = 0; t < DM / 64 - 1; ++t) {
    STAGE1(t + 1, (t + 1) & 1);
    asm volatile("s_waitcnt vmcnt(8)" ::: "memory");
    __builtin_amdgcn_s_barrier();
    __builtin_amdgcn_sched_barrier(0);
    COMPUTE1(t & 1);
    asm volatile("s_waitcnt lgkmcnt(0)" ::: "memory");
    __builtin_amdgcn_sched_barrier(0);
    __builtin_amdgcn_s_barrier();
  }
  asm volatile("s_waitcnt vmcnt(0)" ::: "memory");
  __builtin_amdgcn_s_barrier();
  __builtin_amdgcn_sched_barrier(0);
  COMPUTE1((DM / 64 - 1) & 1);

#pragma unroll
  for (int n = 0; n < 4; n++) {
    int col = n0 + wn + n * 16 + (lane & 15);
    float b1v = b1[e * DF + col];
#pragma unroll
    for (int m = 0; m < 4; m++) {
      int rbase = wm + m * 16 + ((lane >> 4) << 2);
#pragma unroll
      for (int r = 0; r < 4; r++) {
        int grow = row_base + rbase + r;
        if (grow < nrows) {
          float v = acc[m][n][r] + b1v;
          float g = 0.5f * v * (1.f + erff(v * 0.70710678118f));
          hb[(size_t)(roff + grow) * DF + col] = f2bf(g);
        }
      }
    }
  }
}

// ---------------- gemm2: y[slot] = hb[slot] @ W2t^T ----------------
__global__ __launch_bounds__(256) void k_gemm2(const unsigned short* __restrict__ hb,
    const unsigned short* __restrict__ W2t, const int* __restrict__ offsets,
    unsigned short* __restrict__ y) {
  int e = blockIdx.z;
  int roff = offsets[e];
  int nrows = offsets[e + 1] - roff;
  int row_base = blockIdx.y * 128;
  if (row_base >= nrows) return;
  int n0 = blockIdx.x * 128;
  int tid = threadIdx.x, lane = tid & 63, wid = tid >> 6;
  int wm = (wid >> 1) * 64, wn = (wid & 1) * 64;

  __shared__ __align__(16) unsigned short smA[2][128 * 64];
  __shared__ __align__(16) unsigned short smB[2][128 * 64];

  f32x4 acc[4][4];
#pragma unroll
  for (int m = 0; m < 4; m++)
#pragma unroll
    for (int n = 0; n < 4; n++) acc[m][n] = (f32x4)(0.f);

  const unsigned short* Abase = hb + (size_t)(roff + row_base) * DF;
  const unsigned short* Bbase = W2t + (size_t)e * DM * DF + (size_t)n0 * DF;

  const unsigned short* aP[4];
  const unsigned short* bP[4];
  int ldsOff[4];
#pragma unroll
  for (int i = 0; i < 4; i++) {
    int c = tid + i * 256;
    int row = c >> 3;
    int o = ((c & 7) ^ (row & 7)) * 8;
    aP[i] = Abase + (size_t)row * DF + o;   // rows >= nrows read garbage; discarded
    bP[i] = Bbase + (size_t)row * DF + o;
    ldsOff[i] = c * 8;
  }
  int rA[2][4], rB[2][4];
#pragma unroll
  for (int ks = 0; ks < 2; ks++) {
#pragma unroll
    for (int m = 0; m < 4; m++) {
      int rowa = wm + m * 16 + (lane & 15);
      int rowb = wn + m * 16 + (lane & 15);
      int col = ks * 64 + (lane >> 4) * 16;
      rA[ks][m] = rowa * 128 + (col ^ ((rowa & 7) << 4));
      rB[ks][m] = rowb * 128 + (col ^ ((rowb & 7) << 4));
    }
  }

#define STAGE2(kk, p)                                        \
  {                                                          \
    int k0_ = (kk) * 64;                                     \
    _Pragma("unroll")                                        \
    for (int i = 0; i < 4; i++) {                            \
      gload16(aP[i] + k0_, &smA[p][ldsOff[i]]);              \
      gload16(bP[i] + k0_, &smB[p][ldsOff[i]]);              \
    }                                                        \
  }
#define COMPUTE2(p)                                                            \
  {                                                                            \
    const char* A_ = (const char*)smA[p];                                      \
    const char* B_ = (const char*)smB[p];                                      \
    _Pragma("unroll")                                                          \
    for (int ks = 0; ks < 2; ks++) {                                           \
      bf16x8 af[4], bfr[4];                                                    \
      _Pragma("unroll")                                                        \
      for (int m = 0; m < 4; m++) af[m] = *(const bf16x8*)(A_ + rA[ks][m]);    \
      _Pragma("unroll")                                                        \
      for (int n = 0; n < 4; n++) bfr[n] = *(const bf16x8*)(B_ + rB[ks][n]);   \
      _Pragma("unroll")                                                        \
      for (int m = 0; m < 4; m++)                                              \
        _Pragma("unroll")                                                      \
        for (int n = 0; n < 4; n++)                                            \
          acc[m][n] = __builtin_amdgcn_mfma_f32_16x16x32_bf16(af[m], bfr[n],   \
                                                              acc[m][n], 0, 0, 0); \
    }                                                                          \
  }

  STAGE2(0, 0);
  for (int t = 0; t < DF / 64 - 1; ++t) {
    STAGE2(t + 1, (t + 1) & 1);
    asm volatile("s_waitcnt vmcnt(8)" ::: "memory");
    __builtin_amdgcn_s_barrier();
    __builtin_amdgcn_sched_barrier(0);
    COMPUTE2(t & 1);
    asm volatile("s_waitcnt lgkmcnt(0)" ::: "memory");
    __builtin_amdgcn_sched_barrier(0);
    __builtin_amdgcn_s_barrier();
  }
  asm volatile("s_waitcnt vmcnt(0)" ::: "memory");
  __builtin_amdgcn_s_barrier();
  __builtin_amdgcn_sched_barrier(0);
  COMPUTE2((DF / 64 - 1) & 1);

#pragma unroll
  for (int m = 0; m < 4; m++) {
    int rbase = wm + m * 16 + ((lane >> 4) << 2);
#pragma unroll
    for (int r = 0; r < 4; r++) {
      int grow = row_base + rbase + r;
      if (grow < nrows) {
#pragma unroll
        for (int n = 0; n < 4; n++) {
          int col = n0 + wn + n * 16 + (lane & 15);
          y[(size_t)(roff + grow) * DM + col] = f2bf(acc[m][n][r]);
        }
      }
    }
  }
}

// ---------------- combine: out[t] = sum_k w_k * (y[slot_k] + b2[e_k]) ----------------
__global__ __launch_bounds__(256) void k_combine(const int* __restrict__ topi,
    const float* __restrict__ topw, const int* __restrict__ tslot,
    const unsigned short* __restrict__ y, const float* __restrict__ b2,
    float* __restrict__ out) {
  int t = blockIdx.x, tid = threadIdx.x;
  int s0 = tslot[2 * t], s1 = tslot[2 * t + 1];
  int e0 = topi[2 * t], e1 = topi[2 * t + 1];
  float w0 = topw[2 * t], w1 = topw[2 * t + 1];
  int d = tid * 4;
  uint2 ya = *(const uint2*)(y + (size_t)s0 * DM + d);
  uint2 yb = *(const uint2*)(y + (size_t)s1 * DM + d);
  f32x4 bb0 = *(const f32x4*)(b2 + (size_t)e0 * DM + d);
  f32x4 bb1 = *(const f32x4*)(b2 + (size_t)e1 * DM + d);
  f32x4 r;
  r[0] = w0 * (bf2f((unsigned short)(ya.x & 0xffff)) + bb0[0]) + w1 * (bf2f((unsigned short)(yb.x & 0xffff)) + bb1[0]);
  r[1] = w0 * (bf2f((unsigned short)(ya.x >> 16)) + bb0[1]) + w1 * (bf2f((unsigned short)(yb.x >> 16)) + bb1[1]);
  r[2] = w0 * (bf2f((unsigned short)(ya.y & 0xffff)) + bb0[2]) + w1 * (bf2f((unsigned short)(yb.y & 0xffff)) + bb1[2]);
  r[3] = w0 * (bf2f((unsigned short)(ya.y >> 16)) + bb0[3]) + w1 * (bf2f((unsigned short)(yb.y >> 16)) + bb1[3]);
  *(f32x4*)(out + (size_t)t * DM + d) = r;
}

extern "C" void kernel_launch(void* const* d_in, const int* in_sizes, int n_in,
                              void* d_out, int out_size, void* d_ws, size_t ws_size,
                              hipStream_t stream) {
  const float* x  = (const float*)d_in[0];
  const float* Wr = (const float*)d_in[1];
  const float* br = (const float*)d_in[2];
  const float* W1 = (const float*)d_in[3];
  const float* b1 = (const float*)d_in[4];
  const float* W2 = (const float*)d_in[5];
  const float* b2 = (const float*)d_in[6];
  float* out = (float*)d_out;

  char* ws = (char*)d_ws;
  int*   counts  = (int*)(ws + 0);
  int*   cursor  = (int*)(ws + 64);
  int*   offsets = (int*)(ws + 128);
  int*   topi    = (int*)(ws + 256);
  float* topw    = (float*)(ws + 33024);
  int*   perm    = (int*)(ws + 65792);
  int*   tslot   = (int*)(ws + 98560);
  unsigned short* xc  = (unsigned short*)(ws + 164096);               // 4096x1024 bf16 =  8.4 MB
  unsigned short* hb  = (unsigned short*)(ws + 8552704);              // 8192x4096 bf16 = 67.1 MB
  unsigned short* y   = (unsigned short*)(ws + 75661568);             // 8192x1024 bf16 = 16.8 MB
  unsigned short* W1t = (unsigned short*)(ws + 92438784);             // 8x4096x1024 bf16 = 67.1 MB
  unsigned short* W2t = (unsigned short*)(ws + 159547648);            // 8x1024x4096 bf16 = 67.1 MB

  hipMemsetAsync(ws, 0, 256, stream);  // counts, cursor

  k_cvtx<<<T_TOK * DM / (256 * 8), 256, 0, stream>>>(x, xc);
  k_cvtT<<<dim3(DF / 64, DM / 64, NE), 256, 0, stream>>>(W1, W1t, DM, DF);
  k_cvtT<<<dim3(DM / 64, DF / 64, NE), 256, 0, stream>>>(W2, W2t, DF, DM);
  k_router<<<T_TOK, 256, 0, stream>>>(x, Wr, br, topi, topw, counts);
  k_scan<<<1, 64, 0, stream>>>(counts, offsets, out + (size_t)T_TOK * DM);
  k_scatter<<<16, 256, 0, stream>>>(topi, offsets, cursor, perm, tslot);
  k_gemm1<<<dim3(32, 32, 8), 256, 0, stream>>>(xc, W1t, b1, offsets, perm, hb);
  k_gemm2<<<dim3(8, 32, 8), 256, 0, stream>>>(hb, W2t, offsets, y);
  k_combine<<<T_TOK, 256, 0, stream>>>(topi, topw, tslot, y, b2, out);
}